// Round 1
// baseline (1098.028 us; speedup 1.0000x reference)
//
#include <hip/hip_runtime.h>

// Problem constants (fixed by the reference)
#define B_ 8
#define L_ 1024
#define S_ 1024
#define H_ 12
#define E_ 64
#define D_ 64

#define TL 32        // query rows per block
#define NT 512       // 8 waves
#define NSUB 4       // each wave: 4 sub-tiles of 32 s-rows = 128-s chunk

// LDS row pads (elements). Row strides stay 16B-aligned for b128 reads.
#define QW 72        // Qs: 144B rows
#define PSW 40       // Psub: 80B rows (20dw stride -> near-conflict-free b128)
#define OBW 68       // Obuf: f32 rows, 2-way worst case on atomics

typedef short bf8 __attribute__((ext_vector_type(8)));   // 8 x bf16 (4 VGPRs)
typedef float f32x4 __attribute__((ext_vector_type(4))); // MFMA accumulator

static __device__ __forceinline__ unsigned short f2bf(float f) {
  unsigned int u = __builtin_bit_cast(unsigned int, f);
  u += 0x7fffu + ((u >> 16) & 1u);   // round-to-nearest-even
  return (unsigned short)(u >> 16);
}
static __device__ __forceinline__ float bf2f(unsigned short us) {
  unsigned int u = ((unsigned int)us) << 16;
  return __builtin_bit_cast(float, u);
}

__global__ __launch_bounds__(NT, 4) void attn_fused(
    const float* __restrict__ Q, const float* __restrict__ K,
    const float* __restrict__ V, const float* __restrict__ SC,
    float* __restrict__ OUTV, float* __restrict__ OUTA)
{
  // ~34 KB total -> 2 blocks/CU (vs 89.6 KB / 1 block before)
  __shared__ __align__(16) unsigned short Qs[TL * QW];
  __shared__ __align__(16) unsigned short Psub[8][32 * PSW];  // per-wave 32x32 P round-trip
  __shared__ __align__(16) float Obuf[TL * OBW];              // cross-wave O reduction
  __shared__ float rowsum[TL];
  __shared__ float rinv[TL];

  const int t = threadIdx.x;

  // XCD-grouped mapping: blocks sharing (b,h) land on the same XCD so K/V
  // re-reads hit that XCD's L2.
  const int blk = blockIdx.x;
  const int x   = blk & 7;
  const int jj_ = blk >> 3;            // 0..383
  const int bh  = x * 12 + (jj_ >> 5); // 0..95
  const int lt  = jj_ & 31;
  const int b   = bh / H_;
  const int h   = bh - b * H_;
  const int l0  = lt * TL;

  const float scale_h = SC[h];

  const int w    = t >> 6;     // wave 0..7 -> owns s in [w*128, w*128+128)
  const int lane = t & 63;
  const int g    = lane >> 4;  // lane quarter
  const int c16  = lane & 15;
  const int sw   = w * 128;

  // zero LDS accumulators (covered by the Q-stage barrier)
  for (int i = t; i < TL * OBW; i += NT) Obuf[i] = 0.0f;
  if (t < TL) rowsum[t] = 0.0f;

  // ---- stage Q tile: 32 x 64 fp32 -> bf16 LDS (once) ----
  {
    const int r = t >> 4;
    const int c = (t & 15) * 4;
    const float4 q4 = *reinterpret_cast<const float4*>(
        Q + (((size_t)(b * L_ + l0 + r) * H_ + h) * E_ + c));
    unsigned short* dst = &Qs[r * QW + c];
    dst[0] = f2bf(q4.x); dst[1] = f2bf(q4.y);
    dst[2] = f2bf(q4.z); dst[3] = f2bf(q4.w);
  }
  __syncthreads();   // the ONLY barrier before the reductions

  const size_t kbase = ((size_t)b * S_ * H_ + h) * (size_t)E_;  // + s*H*E + e
  const size_t vbase = ((size_t)b * S_ * H_ + h) * (size_t)D_;  // + s*H*D + d

  float psum[2][4] = {{0.f,0.f,0.f,0.f},{0.f,0.f,0.f,0.f}};
  f32x4 oacc[2][4];
#pragma unroll
  for (int m = 0; m < 2; ++m)
#pragma unroll
    for (int n = 0; n < 4; ++n) oacc[m][n] = (f32x4){0.f,0.f,0.f,0.f};

  // packed bf16 P for the A-write: [sub][mtile][ntile][row-pair] = 32 VGPRs
  unsigned int pp[NSUB][2][2][2];

  unsigned short* Pw = &Psub[w][0];

#pragma unroll
  for (int sub = 0; sub < NSUB; ++sub) {
    const int s0 = sw + sub * 32;

    // ---- K B-fragments direct from global (L2-resident, per-wave rows) ----
    bf8 kf[2][2];
#pragma unroll
    for (int n = 0; n < 2; ++n)
#pragma unroll
      for (int ks = 0; ks < 2; ++ks) {
        const float* src =
            K + kbase + (size_t)(s0 + n * 16 + c16) * (H_ * E_) + ks * 32 + g * 8;
        const float4 a0 = *reinterpret_cast<const float4*>(src);
        const float4 a1 = *reinterpret_cast<const float4*>(src + 4);
        bf8 kk;
        kk[0] = (short)f2bf(a0.x); kk[1] = (short)f2bf(a0.y);
        kk[2] = (short)f2bf(a0.z); kk[3] = (short)f2bf(a0.w);
        kk[4] = (short)f2bf(a1.x); kk[5] = (short)f2bf(a1.y);
        kk[6] = (short)f2bf(a1.z); kk[7] = (short)f2bf(a1.w);
        kf[n][ks] = kk;
      }

    // ---- Q A-fragments from LDS (compiler CSEs across subs as pressure allows) ----
    bf8 qf[2][2];
#pragma unroll
    for (int m = 0; m < 2; ++m)
#pragma unroll
      for (int ks = 0; ks < 2; ++ks)
        qf[m][ks] = *reinterpret_cast<const bf8*>(
            &Qs[(m * 16 + c16) * QW + ks * 32 + g * 8]);

    // ---- QK^T (8 MFMA) ----
    f32x4 sacc[2][2];
#pragma unroll
    for (int m = 0; m < 2; ++m)
#pragma unroll
      for (int n = 0; n < 2; ++n) sacc[m][n] = (f32x4){0.f,0.f,0.f,0.f};
#pragma unroll
    for (int m = 0; m < 2; ++m)
#pragma unroll
      for (int n = 0; n < 2; ++n)
#pragma unroll
        for (int ks = 0; ks < 2; ++ks)
          sacc[m][n] = __builtin_amdgcn_mfma_f32_16x16x32_bf16(
              qf[m][ks], kf[n][ks], sacc[m][n], 0, 0, 0);

    // ---- exp + diagonal mask + pack + per-wave Psub write ----
#pragma unroll
    for (int m = 0; m < 2; ++m)
#pragma unroll
      for (int n = 0; n < 2; ++n) {
        unsigned int pk0 = 0, pk1 = 0;
#pragma unroll
        for (int r = 0; r < 4; ++r) {
          const int lrow = m * 16 + g * 4 + r;        // local q row
          const int scol = s0 + n * 16 + c16;         // global key col
          float p = __expf(sacc[m][n][r] * scale_h);
          if (scol == l0 + lrow) p = 0.0f;            // LSA diagonal mask
          psum[m][r] += p;
          const unsigned int pb = f2bf(p);
          if (r == 0) pk0 = pb;
          else if (r == 1) pk0 |= pb << 16;
          else if (r == 2) pk1 = pb;
          else pk1 |= pb << 16;
          Pw[lrow * PSW + n * 16 + c16] = (unsigned short)pb;
        }
        pp[sub][m][n][0] = pk0;
        pp[sub][m][n][1] = pk1;
      }

    // ---- PV: A-frags via wave-internal LDS round-trip (layout fixup),
    //      B-frags (V columns) direct from global. No barriers. ----
    bf8 paf[2];
#pragma unroll
    for (int m = 0; m < 2; ++m)
      paf[m] = *reinterpret_cast<const bf8*>(&Pw[(m * 16 + c16) * PSW + g * 8]);

#pragma unroll
    for (int n = 0; n < 4; ++n) {
      const float* vsrc =
          V + vbase + (size_t)(s0 + g * 8) * (H_ * D_) + n * 16 + c16;
      bf8 vb;
#pragma unroll
      for (int j = 0; j < 8; ++j)
        vb[j] = (short)f2bf(vsrc[(size_t)j * (H_ * D_)]);
#pragma unroll
      for (int m = 0; m < 2; ++m)
        oacc[m][n] = __builtin_amdgcn_mfma_f32_16x16x32_bf16(
            paf[m], vb, oacc[m][n], 0, 0, 0);
    }
  }

  // ---- cross-wave O reduction (LDS atomics) ----
#pragma unroll
  for (int m = 0; m < 2; ++m)
#pragma unroll
    for (int n = 0; n < 4; ++n)
#pragma unroll
      for (int r = 0; r < 4; ++r)
        atomicAdd(&Obuf[(m * 16 + g * 4 + r) * OBW + n * 16 + c16],
                  oacc[m][n][r]);

  // ---- row sums: 16-lane shuffle reduce, then one atomic per row per wave ----
#pragma unroll
  for (int m = 0; m < 2; ++m)
#pragma unroll
    for (int r = 0; r < 4; ++r) {
      float v = psum[m][r];
      v += __shfl_xor(v, 8, 16);
      v += __shfl_xor(v, 4, 16);
      v += __shfl_xor(v, 2, 16);
      v += __shfl_xor(v, 1, 16);
      if (c16 == 0) atomicAdd(&rowsum[m * 16 + g * 4 + r], v);
    }
  __syncthreads();
  if (t < TL) rinv[t] = 1.0f / rowsum[t];
  __syncthreads();

  // ---- A write: straight from packed registers (L2 merges 64B segments) ----
  {
    const size_t abase = (((size_t)(b * H_ + h)) * L_ + l0) * S_;
    float rv[2][4];
#pragma unroll
    for (int m = 0; m < 2; ++m)
#pragma unroll
      for (int r = 0; r < 4; ++r) rv[m][r] = rinv[m * 16 + g * 4 + r];
#pragma unroll
    for (int sub = 0; sub < NSUB; ++sub)
#pragma unroll
      for (int m = 0; m < 2; ++m)
#pragma unroll
        for (int n = 0; n < 2; ++n)
#pragma unroll
          for (int k = 0; k < 2; ++k) {
            const unsigned int pk = pp[sub][m][n][k];
            const int r0 = k * 2, r1 = k * 2 + 1;
            const size_t col = (size_t)(sw + sub * 32 + n * 16 + c16);
            OUTA[abase + (size_t)(m * 16 + g * 4 + r0) * S_ + col] =
                bf2f((unsigned short)(pk & 0xffffu)) * rv[m][r0];
            OUTA[abase + (size_t)(m * 16 + g * 4 + r1) * S_ + col] =
                bf2f((unsigned short)(pk >> 16)) * rv[m][r1];
          }
  }

  // ---- O write (normalize here: P was unnormalized) ----
  {
    const int r = t >> 4;
    const int d = (t & 15) * 4;
    const float ri = rinv[r];
    float4 o;
    o.x = Obuf[r * OBW + d + 0] * ri;
    o.y = Obuf[r * OBW + d + 1] * ri;
    o.z = Obuf[r * OBW + d + 2] * ri;
    o.w = Obuf[r * OBW + d + 3] * ri;
    *reinterpret_cast<float4*>(
        OUTV + (((size_t)(b * L_ + l0 + r)) * H_ + h) * D_ + d) = o;
  }
}

extern "C" void kernel_launch(void* const* d_in, const int* in_sizes, int n_in,
                              void* d_out, int out_size, void* d_ws, size_t ws_size,
                              hipStream_t stream) {
  (void)in_sizes; (void)n_in; (void)out_size; (void)d_ws; (void)ws_size;
  const float* Q  = (const float*)d_in[0];
  const float* K  = (const float*)d_in[1];
  const float* V  = (const float*)d_in[2];
  const float* SC = (const float*)d_in[3];
  float* OUTV = (float*)d_out;
  float* OUTA = OUTV + (size_t)B_ * L_ * H_ * D_;   // tuple order: (V, A)

  const dim3 grid(B_ * H_ * (L_ / TL));  // 3072 blocks
  attn_fused<<<grid, NT, 0, stream>>>(Q, K, V, SC, OUTV, OUTA);
}